// Round 7
// baseline (1452.858 us; speedup 1.0000x reference)
//
#include <hip/hip_runtime.h>

#define M_EDGES 150000
#define NN_NODES 50000
#define N_TRIS  100000
#define F 256
#define NLAYERS 4

// virtual A rows = [x (150k) ; s (50k) ; q (100k)], 128-row tiles
#define T0 1172                  // ceil(150000/128)  -> gemm_y1_relu
#define T1 391                   // ceil(50000/128)   -> gemm_zw seg1
#define T2 782                   // ceil(100000/128)  -> gemm_zw seg2
#define TZW (T1 + T2)            // 1173
#define GR_PAD 1176              // 8 * 147, grid for both gemms
#define TPX8 147                 // tiles per XCD

typedef __attribute__((ext_vector_type(8))) __bf16 bf16x8;
typedef __attribute__((ext_vector_type(4))) float f32x4;

__device__ inline unsigned short f2bf(float f) {
    unsigned int u = __float_as_uint(f);
    u += 0x7fff + ((u >> 16) & 1);
    return (unsigned short)(u >> 16);
}
__device__ inline float bf2f(unsigned short h) {
    return __uint_as_float(((unsigned int)h) << 16);
}

__device__ inline void async16(const void* g, void* l) {
    __builtin_amdgcn_global_load_lds(
        (const __attribute__((address_space(1))) void*)g,
        (__attribute__((address_space(3))) void*)l, 16, 0, 0);
}

// ---------------------------------------------------------------------------
// R7: occupancy for the gather epilogue. R6's shfl-prefetch regressed
// (137->183us, VGPR 64->68): the latency is in the z/w ROW GATHERS (L2-miss,
// 77MB hot set vs 4MB/XCD L2), not the metadata chain -> the fix is MLP via
// more resident waves, not chain-shortening. Revert epilogue to R5 inline
// form; process the C-tile in TWO 64-row halves through a 32KB LDS buffer
// (was 64KB) -> 2 -> 4 resident blocks/CU (wave cap), nearly the whole
// 1176-block grid co-resident. agg_fused keeps R6's one-shot prefetch
// (neutral-positive).
// ---------------------------------------------------------------------------

// shared K-loop body (single 24KB buffer, R0-style sync: best measured)
#define GEMM_KLOOP(Asrc, wsel, nrows)                                       \
    for (int k0 = 0; k0 < 256; k0 += 32) {                                  \
        {                                                                   \
            int row = tid >> 2;                                             \
            int g   = (tid & 3) ^ ((row >> 1) & 3);                         \
            int gr  = bm0 + row;                                            \
            if (gr > (nrows) - 1) gr = (nrows) - 1;                         \
            async16((Asrc) + (size_t)gr * 256 + k0 + g * 8,                 \
                    As + (size_t)wbase * 8);                                \
        }                                                                   \
        _Pragma("unroll")                                                   \
        for (int ss = 0; ss < 2; ss++) {                                    \
            int i   = ss * 512 + tid;                                       \
            int row = i >> 2;                                               \
            int g   = (i & 3) ^ ((row >> 1) & 3);                           \
            async16((wsel) + (size_t)row * 256 + k0 + g * 8,                \
                    Bs + (size_t)(ss * 512 + wbase) * 8);                   \
        }                                                                   \
        asm volatile("s_waitcnt vmcnt(0)" ::: "memory");                    \
        __syncthreads();                                                    \
        bf16x8 a[4], bfr[4];                                                \
        _Pragma("unroll")                                                   \
        for (int i = 0; i < 4; i++) {                                       \
            int rr = wm * 64 + i * 16 + lm;                                 \
            a[i] = *(const bf16x8*)(As + rr * 32 +                          \
                                    ((lh ^ ((rr >> 1) & 3)) * 8));          \
        }                                                                   \
        _Pragma("unroll")                                                   \
        for (int j = 0; j < 4; j++) {                                       \
            int rr = wn * 64 + j * 16 + lm;                                 \
            bfr[j] = *(const bf16x8*)(Bs + rr * 32 +                        \
                                      ((lh ^ ((rr >> 1) & 3)) * 8));        \
        }                                                                   \
        _Pragma("unroll")                                                   \
        for (int i = 0; i < 4; i++)                                         \
            _Pragma("unroll")                                               \
            for (int j = 0; j < 4; j++)                                     \
                cacc[i][j] = __builtin_amdgcn_mfma_f32_16x16x32_bf16(       \
                    bfr[j], a[i], cacc[i][j], 0, 0, 0);                     \
        __syncthreads();                                                    \
    }

__global__ __launch_bounds__(512) void gemm_zw(
    const unsigned short* __restrict__ sb,
    const unsigned short* __restrict__ qb,
    const unsigned short* __restrict__ wt,
    unsigned short* __restrict__ zb,
    unsigned short* __restrict__ wb)
{
    __shared__ unsigned short As[128 * 32];   // 8 KB
    __shared__ unsigned short Bs[256 * 32];   // 16 KB

    const int b    = blockIdx.x;
    const int tile = (b & 7) * TPX8 + (b >> 3);
    if (tile >= TZW) return;

    int seg, tloc;
    if (tile < T1) { seg = 1; tloc = tile; }
    else           { seg = 2; tloc = tile - T1; }
    const unsigned short* Asrc = (seg == 1) ? sb : qb;
    const int nrows = (seg == 1) ? NN_NODES : N_TRIS;
    const unsigned short* wsel = wt + seg * 65536;
    unsigned short* dst = (seg == 1) ? zb : wb;

    const int tid  = threadIdx.x;
    const int bm0  = tloc * 128;
    const int wid  = tid >> 6;
    const int lane = tid & 63;
    const int lm   = lane & 15;
    const int lh   = lane >> 4;
    const int wm   = wid >> 2;
    const int wn   = wid & 3;
    const int wbase = tid & ~63;

    f32x4 cacc[4][4];
#pragma unroll
    for (int i = 0; i < 4; i++)
#pragma unroll
        for (int j = 0; j < 4; j++) cacc[i][j] = (f32x4){0.f, 0.f, 0.f, 0.f};

    GEMM_KLOOP(Asrc, wsel, nrows)

#pragma unroll
    for (int i = 0; i < 4; i++) {
        int grow = bm0 + wm * 64 + i * 16 + lm;
        if (grow < nrows) {
#pragma unroll
            for (int j = 0; j < 4; j++) {
                int col = wn * 64 + j * 16 + lh * 4;
                ushort4 r;
                r.x = f2bf(cacc[i][j][0]);
                r.y = f2bf(cacc[i][j][1]);
                r.z = f2bf(cacc[i][j][2]);
                r.w = f2bf(cacc[i][j][3]);
                *(ushort4*)(dst + (size_t)grow * 256 + col) = r;
            }
        }
    }
}

__global__ __launch_bounds__(512) void gemm_y1_relu(
    unsigned short* __restrict__ xb,          // A source AND x_next dst
    const unsigned short* __restrict__ wt,    // seg0 weights (W1)
    const unsigned short* __restrict__ wb,    // tri rows (q@W2)
    const unsigned short* __restrict__ zb,    // node rows (s@W0)
    const int* __restrict__ en,
    const int* __restrict__ eoff,
    const int* __restrict__ eadj,
    const float* __restrict__ wl,
    float* __restrict__ p,
    int last)
{
    // 32 KB total: K-loop uses [0,24KB) as As|Bs; epilogue reuses the whole
    // buffer as a 64x256 bf16 half-C-tile (two passes).
    __shared__ __align__(16) unsigned short smem[64 * 256];
    unsigned short* const As = smem;              // 128*32 = 8KB
    unsigned short* const Bs = smem + 128 * 32;   // 256*32 = 16KB

    const int b    = blockIdx.x;
    const int tile = (b & 7) * TPX8 + (b >> 3);
    if (tile >= T0) return;

    const int tid  = threadIdx.x;
    const int bm0  = tile * 128;
    const int wid  = tid >> 6;
    const int lane = tid & 63;
    const int lm   = lane & 15;
    const int lh   = lane >> 4;
    const int wm   = wid >> 2;
    const int wn   = wid & 3;
    const int wbase = tid & ~63;

    f32x4 cacc[4][4];
#pragma unroll
    for (int i = 0; i < 4; i++)
#pragma unroll
        for (int j = 0; j < 4; j++) cacc[i][j] = (f32x4){0.f, 0.f, 0.f, 0.f};

    GEMM_KLOOP(xb, wt, M_EDGES)

    const int f = lane * 4;
    for (int h = 0; h < 2; h++) {
        __syncthreads();   // previous half's LDS reads done before overwrite
        // --- stage this half's 64 rows (owned by waves with wm==h),
        // bf16, XOR-swizzled by local row ---
        if (wm == h) {
#pragma unroll
            for (int i = 0; i < 4; i++) {
                int lrow = i * 16 + lm;                  // 0..63 local
                int key  = (lrow & 7) << 4;
#pragma unroll
                for (int j = 0; j < 4; j++) {
                    int colb = wn * 128 + j * 32 + lh * 8;
                    ushort4 r;
                    r.x = f2bf(cacc[i][j][0]);
                    r.y = f2bf(cacc[i][j][1]);
                    r.z = f2bf(cacc[i][j][2]);
                    r.w = f2bf(cacc[i][j][3]);
                    *(ushort4*)((char*)smem + (size_t)lrow * 512 +
                                (colb ^ key)) = r;
                }
            }
        }
        __syncthreads();

        // --- gather-process 64 rows: one edge per wave per iteration,
        // fully-coalesced 512B/wave row loads (R5 pattern) ---
        for (int r8 = 0; r8 < 8; r8++) {
            int lr = r8 * 8 + wid;                       // 0..63 local
            int e  = bm0 + h * 64 + lr;
            if (e >= M_EDGES) break;   // wave-uniform; barriers are outside
            ushort4 yv = *(const ushort4*)((const char*)smem +
                          (size_t)lr * 512 + ((lane * 8) ^ ((lr & 7) << 4)));
            int u = en[2 * e], v = en[2 * e + 1];
            ushort4 zv4 = *(const ushort4*)(zb + (size_t)v * 256 + f);
            ushort4 zu4 = *(const ushort4*)(zb + (size_t)u * 256 + f);
            float sx = bf2f(yv.x) + bf2f(zv4.x) - bf2f(zu4.x);
            float sy = bf2f(yv.y) + bf2f(zv4.y) - bf2f(zu4.y);
            float sz = bf2f(yv.z) + bf2f(zv4.z) - bf2f(zu4.z);
            float sw = bf2f(yv.w) + bf2f(zv4.w) - bf2f(zu4.w);
            int beg = eoff[e], end = eoff[e + 1];
            int i2 = beg;
            for (; i2 + 1 < end; i2 += 2) {
                int ta = eadj[i2], tb = eadj[i2 + 1];
                float sa  = (ta & 1) ? -1.f : 1.f;
                float sgb = (tb & 1) ? -1.f : 1.f;
                ushort4 wa  = *(const ushort4*)(wb + (size_t)(ta >> 1) * 256 + f);
                ushort4 wbv = *(const ushort4*)(wb + (size_t)(tb >> 1) * 256 + f);
                sx += sa * bf2f(wa.x) + sgb * bf2f(wbv.x);
                sy += sa * bf2f(wa.y) + sgb * bf2f(wbv.y);
                sz += sa * bf2f(wa.z) + sgb * bf2f(wbv.z);
                sw += sa * bf2f(wa.w) + sgb * bf2f(wbv.w);
            }
            if (i2 < end) {
                int ta = eadj[i2];
                float sa = (ta & 1) ? -1.f : 1.f;
                ushort4 wa = *(const ushort4*)(wb + (size_t)(ta >> 1) * 256 + f);
                sx += sa * bf2f(wa.x);
                sy += sa * bf2f(wa.y);
                sz += sa * bf2f(wa.z);
                sw += sa * bf2f(wa.w);
            }
            sx = fmaxf(sx, 0.f);
            sy = fmaxf(sy, 0.f);
            sz = fmaxf(sz, 0.f);
            sw = fmaxf(sw, 0.f);
            if (!last) {
                ushort4 r;
                r.x = f2bf(sx); r.y = f2bf(sy); r.z = f2bf(sz); r.w = f2bf(sw);
                *(ushort4*)(xb + (size_t)e * 256 + f) = r;
            } else {
                float4 wv = *(const float4*)(wl + f);
                float s = sx * wv.x + sy * wv.y + sz * wv.z + sw * wv.w;
#pragma unroll
                for (int off = 32; off > 0; off >>= 1)
                    s += __shfl_down(s, off, 64);
                if (lane == 0) p[e] = s;
            }
        }
    }
}

// ---------------------------------------------------------------------------
// CSR build
// ---------------------------------------------------------------------------
__global__ __launch_bounds__(256) void count_nodes(
    const int* __restrict__ en, int* __restrict__ cnt)
{
    int e = blockIdx.x * 256 + threadIdx.x;
    if (e < M_EDGES) {
        atomicAdd(&cnt[en[2 * e]], 1);
        atomicAdd(&cnt[en[2 * e + 1]], 1);
    }
}

__global__ __launch_bounds__(256) void count_tris(
    const int* __restrict__ te, int* __restrict__ cnt)
{
    int t = blockIdx.x * 256 + threadIdx.x;
    if (t < N_TRIS) {
#pragma unroll
        for (int k = 0; k < 3; k++) atomicAdd(&cnt[te[3 * t + k]], 1);
    }
}

__global__ __launch_bounds__(256) void scan_block(
    const int* __restrict__ cnt, int* __restrict__ off,
    int* __restrict__ partial, int n)
{
    __shared__ int s[256];
    int t = threadIdx.x;
    int gid = blockIdx.x * 256 + t;
    int v = (gid < n) ? cnt[gid] : 0;
    s[t] = v;
    __syncthreads();
    for (int o = 1; o < 256; o <<= 1) {
        int x = (t >= o) ? s[t - o] : 0;
        __syncthreads();
        s[t] += x;
        __syncthreads();
    }
    if (gid < n) off[gid] = s[t] - v;
    if (t == 255) partial[blockIdx.x] = s[255];
}

__global__ __launch_bounds__(1024) void scan_partial(int* __restrict__ partial, int nb)
{
    __shared__ int s[1024];
    int t = threadIdx.x;
    int v = (t < nb) ? partial[t] : 0;
    s[t] = v;
    __syncthreads();
    for (int o = 1; o < 1024; o <<= 1) {
        int x = (t >= o) ? s[t - o] : 0;
        __syncthreads();
        s[t] += x;
        __syncthreads();
    }
    if (t < nb) partial[t] = s[t] - v;
}

__global__ __launch_bounds__(256) void scan_add(
    int* __restrict__ off, int* __restrict__ cursor,
    const int* __restrict__ partial, int n, int total)
{
    int gid = blockIdx.x * 256 + threadIdx.x;
    if (gid == 0) off[n] = total;
    if (gid < n) {
        int o = off[gid] + partial[blockIdx.x];
        off[gid] = o;
        cursor[gid] = o;
    }
}

__global__ __launch_bounds__(256) void fill_nodes(
    const int* __restrict__ en, int* __restrict__ cursor, int* __restrict__ adj)
{
    int e = blockIdx.x * 256 + threadIdx.x;
    if (e < M_EDGES) {
        int u = en[2 * e], v = en[2 * e + 1];
        adj[atomicAdd(&cursor[u], 1)] = (e << 1);        // u endpoint: minus
        adj[atomicAdd(&cursor[v], 1)] = (e << 1) | 1;    // v endpoint: plus
    }
}

__global__ __launch_bounds__(256) void fill_tris(
    const int* __restrict__ te, const int* __restrict__ ts,
    int* __restrict__ cursor, int* __restrict__ adj)
{
    int t = blockIdx.x * 256 + threadIdx.x;
    if (t < N_TRIS) {
#pragma unroll
        for (int k = 0; k < 3; k++) {
            int e = te[3 * t + k];
            int neg = (ts[3 * t + k] < 0) ? 1 : 0;
            adj[atomicAdd(&cursor[e], 1)] = (t << 1) | neg;
        }
    }
}

// ---------------------------------------------------------------------------
// Aggregation pass (pre-GEMM):
//   blocks [0, ZN_BLOCKS)        : s[n] = sum (+/-) x[e]   (node CSR)
//   blocks [ZN_BLOCKS, +WT)      : q[t] = sum s_k * x[e_k] (tri direct)
// ---------------------------------------------------------------------------
#define ZN_BLOCKS (NN_NODES / 4)
#define WT_BLOCKS (N_TRIS / 4)

__global__ __launch_bounds__(256) void agg_fused(
    const unsigned short* __restrict__ xb,
    const int* __restrict__ noff,
    const int* __restrict__ nadj,
    unsigned short* __restrict__ sbuf,
    const int* __restrict__ te,
    const int* __restrict__ ts,
    unsigned short* __restrict__ qbuf)
{
    int lane = threadIdx.x & 63;
    int f = lane * 4;
    if (blockIdx.x < ZN_BLOCKS) {
        int n = blockIdx.x * 4 + (threadIdx.x >> 6);
        int beg = noff[n], end = noff[n + 1];
        int deg = end - beg;
        // one-shot adjacency prefetch: lane l holds entry l (valid l<deg)
        int cl = beg + lane;
        if (cl > 2 * M_EDGES - 1) cl = 2 * M_EDGES - 1;
        int entL = nadj[cl];
        int dmax = (deg < 64) ? deg : 64;
        float ax = 0.f, ay = 0.f, az = 0.f, aw = 0.f;
        int j = 0;
        for (; j + 1 < dmax; j += 2) {
            int ea = __shfl(entL, j, 64);
            int eb = __shfl(entL, j + 1, 64);
            float sa = (ea & 1) ? 1.f : -1.f;
            float sgb = (eb & 1) ? 1.f : -1.f;
            ushort4 va = *(const ushort4*)(xb + (size_t)(ea >> 1) * 256 + f);
            ushort4 vb = *(const ushort4*)(xb + (size_t)(eb >> 1) * 256 + f);
            ax += sa * bf2f(va.x) + sgb * bf2f(vb.x);
            ay += sa * bf2f(va.y) + sgb * bf2f(vb.y);
            az += sa * bf2f(va.z) + sgb * bf2f(vb.z);
            aw += sa * bf2f(va.w) + sgb * bf2f(vb.w);
        }
        if (j < dmax) {
            int ea = __shfl(entL, j, 64);
            float sa = (ea & 1) ? 1.f : -1.f;
            ushort4 va = *(const ushort4*)(xb + (size_t)(ea >> 1) * 256 + f);
            ax += sa * bf2f(va.x);
            ay += sa * bf2f(va.y);
            az += sa * bf2f(va.z);
            aw += sa * bf2f(va.w);
        }
        for (int i = beg + 64; i < end; i++) {   // rare deg>64 fallback
            int ea = nadj[i];
            float sa = (ea & 1) ? 1.f : -1.f;
            ushort4 va = *(const ushort4*)(xb + (size_t)(ea >> 1) * 256 + f);
            ax += sa * bf2f(va.x);
            ay += sa * bf2f(va.y);
            az += sa * bf2f(va.z);
            aw += sa * bf2f(va.w);
        }
        ushort4 r;
        r.x = f2bf(ax); r.y = f2bf(ay); r.z = f2bf(az); r.w = f2bf(aw);
        *(ushort4*)(sbuf + (size_t)n * 256 + f) = r;
    } else {
        int t = (blockIdx.x - ZN_BLOCKS) * 4 + (threadIdx.x >> 6);
        int e0 = te[3 * t + 0], e1 = te[3 * t + 1], e2 = te[3 * t + 2];
        float s0 = (float)ts[3 * t + 0];
        float s1 = (float)ts[3 * t + 1];
        float s2 = (float)ts[3 * t + 2];
        ushort4 a4 = *(const ushort4*)(xb + (size_t)e0 * 256 + f);
        ushort4 b4 = *(const ushort4*)(xb + (size_t)e1 * 256 + f);
        ushort4 d4 = *(const ushort4*)(xb + (size_t)e2 * 256 + f);
        ushort4 r;
        r.x = f2bf(s0 * bf2f(a4.x) + s1 * bf2f(b4.x) + s2 * bf2f(d4.x));
        r.y = f2bf(s0 * bf2f(a4.y) + s1 * bf2f(b4.y) + s2 * bf2f(d4.y));
        r.z = f2bf(s0 * bf2f(a4.z) + s1 * bf2f(b4.z) + s2 * bf2f(d4.z));
        r.w = f2bf(s0 * bf2f(a4.w) + s1 * bf2f(b4.w) + s2 * bf2f(d4.w));
        *(ushort4*)(qbuf + (size_t)t * 256 + f) = r;
    }
}

__global__ __launch_bounds__(256) void out_nodes(
    const float* __restrict__ p,
    const int* __restrict__ noff,
    const int* __restrict__ nadj,
    float* __restrict__ out)
{
    int n = blockIdx.x * 256 + threadIdx.x;
    if (n >= NN_NODES) return;
    int beg = noff[n], end = noff[n + 1];
    float s = 0.f;
    for (int i = beg; i < end; i++) {
        int ent = nadj[i];
        float sg = (ent & 1) ? 1.f : -1.f;
        s += sg * p[ent >> 1];
    }
    out[n] = s;
}

// ---------------------------------------------------------------------------
// Conversions
// ---------------------------------------------------------------------------
__global__ __launch_bounds__(256) void cvt_x(
    const float* __restrict__ x, unsigned short* __restrict__ xb)
{
    int idx = blockIdx.x * 256 + threadIdx.x;
    float4 v = *(const float4*)(x + (size_t)idx * 4);
    ushort4 r;
    r.x = f2bf(v.x); r.y = f2bf(v.y); r.z = f2bf(v.z); r.w = f2bf(v.w);
    *(ushort4*)(xb + (size_t)idx * 4) = r;
}

// wt[l][seg][n][k], seg order = (W1, W0, W2) matching GEMM segments
__global__ __launch_bounds__(256) void cvt_w(
    const float* __restrict__ W0, const float* __restrict__ W1,
    const float* __restrict__ W2, unsigned short* __restrict__ wt)
{
    int idx = blockIdx.x * 256 + threadIdx.x;   // 4*3*65536 total
    int l = idx / (3 * 65536);
    int rem = idx - l * (3 * 65536);
    int seg = rem >> 16;
    int n = (rem >> 8) & 255;
    int k = rem & 255;
    const float* src = (seg == 0) ? W1 : (seg == 1) ? W0 : W2;
    wt[idx] = f2bf(src[(size_t)l * 65536 + k * 256 + n]);
}

extern "C" void kernel_launch(void* const* d_in, const int* in_sizes, int n_in,
                              void* d_out, int out_size, void* d_ws, size_t ws_size,
                              hipStream_t stream)
{
    const float* x0  = (const float*)d_in[0];
    const float* W0s = (const float*)d_in[1];
    const float* W1s = (const float*)d_in[2];
    const float* W2s = (const float*)d_in[3];
    const float* WL  = (const float*)d_in[4];
    const int*   en  = (const int*)d_in[5];
    const int*   te  = (const int*)d_in[6];
    const int*   ts  = (const int*)d_in[7];
    float* out = (float*)d_out;

    const size_t MF = (size_t)M_EDGES * F;
    unsigned short* xb = (unsigned short*)d_ws;          // MF
    unsigned short* y1 = xb + MF;                        // MF (unused now)
    unsigned short* sbuf = y1 + MF;                      // NN*256
    unsigned short* qbuf = sbuf + (size_t)NN_NODES * 256;// N_TRIS*256
    unsigned short* wt = qbuf + (size_t)N_TRIS * 256;    // 4*3*65536
    unsigned short* wb = wt + (size_t)4 * 3 * 65536;     // N_TRIS*256
    unsigned short* zb = wb + (size_t)N_TRIS * 256;      // NN*256
    float* p = (float*)(zb + (size_t)NN_NODES * 256);    // M f32
    int* noff = (int*)(p + M_EDGES);                     // NN+1
    int* ncur = noff + (NN_NODES + 1);                   // NN
    int* nadj = ncur + NN_NODES;                         // 2*M
    int* eoff = nadj + 2 * M_EDGES;                      // M+1
    int* ecur = eoff + (M_EDGES + 1);                    // M
    int* eadj = ecur + M_EDGES;                          // 3*N_TRIS
    int* part = eadj + 3 * N_TRIS;                       // 1024

    cvt_w<<<(4 * 3 * 65536) / 256, 256, 0, stream>>>(W0s, W1s, W2s, wt);
    cvt_x<<<(int)(MF / 4 / 256), 256, 0, stream>>>(x0, xb);

    const int nbN = (NN_NODES + 255) / 256;
    const int nbE = (M_EDGES + 255) / 256;
    hipMemsetAsync(ncur, 0, NN_NODES * sizeof(int), stream);
    hipMemsetAsync(ecur, 0, M_EDGES * sizeof(int), stream);
    count_nodes<<<nbE, 256, 0, stream>>>(en, ncur);
    count_tris<<<(N_TRIS + 255) / 256, 256, 0, stream>>>(te, ecur);
    scan_block<<<nbN, 256, 0, stream>>>(ncur, noff, part, NN_NODES);
    scan_partial<<<1, 1024, 0, stream>>>(part, nbN);
    scan_add<<<nbN, 256, 0, stream>>>(noff, ncur, part, NN_NODES, 2 * M_EDGES);
    fill_nodes<<<nbE, 256, 0, stream>>>(en, ncur, nadj);
    scan_block<<<nbE, 256, 0, stream>>>(ecur, eoff, part, M_EDGES);
    scan_partial<<<1, 1024, 0, stream>>>(part, nbE);
    scan_add<<<nbE, 256, 0, stream>>>(eoff, ecur, part, M_EDGES, 3 * N_TRIS);
    fill_tris<<<(N_TRIS + 255) / 256, 256, 0, stream>>>(te, ts, ecur, eadj);

    for (int l = 0; l < NLAYERS; l++) {
        agg_fused<<<ZN_BLOCKS + WT_BLOCKS, 256, 0, stream>>>(
            xb, noff, nadj, sbuf, te, ts, qbuf);
        gemm_zw<<<GR_PAD, 512, 0, stream>>>(
            sbuf, qbuf, wt + (size_t)l * 3 * 65536, zb, wb);
        gemm_y1_relu<<<GR_PAD, 512, 0, stream>>>(
            xb, wt + (size_t)l * 3 * 65536, wb, zb, en, eoff, eadj,
            WL, p, (l == NLAYERS - 1) ? 1 : 0);
    }

    out_nodes<<<(NN_NODES + 255) / 256, 256, 0, stream>>>(p, noff, nadj, out);
}

// Round 8
// 1209.962 us; speedup vs baseline: 1.2007x; 1.2007x over previous
//
#include <hip/hip_runtime.h>

#define M_EDGES 150000
#define NN_NODES 50000
#define N_TRIS  100000
#define F 256
#define NLAYERS 4

// gemm_zw: 128-row tiles over [s (50k) ; q (100k)]
#define T1 391                   // ceil(50000/128)
#define T2 782                   // ceil(100000/128)
#define TZW (T1 + T2)            // 1173
#define ZW_PAD 1176              // 8 * 147
#define TPXZW 147
// gemm_y1_relu: 64-row tiles over x (150k)
#define T0_64 2344               // ceil(150000/64) = 2344 = 8*293 exactly
#define TPX64 293

typedef __attribute__((ext_vector_type(8))) __bf16 bf16x8;
typedef __attribute__((ext_vector_type(4))) float f32x4;

__device__ inline unsigned short f2bf(float f) {
    unsigned int u = __float_as_uint(f);
    u += 0x7fff + ((u >> 16) & 1);
    return (unsigned short)(u >> 16);
}
__device__ inline float bf2f(unsigned short h) {
    return __uint_as_float(((unsigned int)h) << 16);
}

__device__ inline void async16(const void* g, void* l) {
    __builtin_amdgcn_global_load_lds(
        (const __attribute__((address_space(1))) void*)g,
        (__attribute__((address_space(3))) void*)l, 16, 0, 0);
}

// ---------------------------------------------------------------------------
// R8: gather-MLP via small tiles. R5 (best fused, 137us) was gated by the
// 64KB C-tile LDS -> 2 blocks/CU -> ~16 waves of gather parallelism ->
// 1.38 TB/s effective (same gather pattern reaches ~4.3 TB/s at full
// occupancy in agg/standalone-relu). R6/R7 failed by extending cacc
// liveness (VGPR 68/100). Now: gemm_y1_relu uses BM=64 x 256-thread blocks
// -> C-tile 32KB, cacc fully retired to LDS before any gather (VGPR ~64-90)
// -> 4-5 blocks/CU; plus 2-edge-interleaved gather loop (2 independent
// eadj->w chains per wave iteration). ~2.5x outstanding gathers vs R5.
// ---------------------------------------------------------------------------

__global__ __launch_bounds__(512) void gemm_zw(
    const unsigned short* __restrict__ sb,
    const unsigned short* __restrict__ qb,
    const unsigned short* __restrict__ wt,
    unsigned short* __restrict__ zb,
    unsigned short* __restrict__ wb)
{
    __shared__ unsigned short As[128 * 32];   // 8 KB
    __shared__ unsigned short Bs[256 * 32];   // 16 KB

    const int b    = blockIdx.x;
    const int tile = (b & 7) * TPXZW + (b >> 3);
    if (tile >= TZW) return;

    int seg, tloc;
    if (tile < T1) { seg = 1; tloc = tile; }
    else           { seg = 2; tloc = tile - T1; }
    const unsigned short* Asrc = (seg == 1) ? sb : qb;
    const int nrows = (seg == 1) ? NN_NODES : N_TRIS;
    const unsigned short* wsel = wt + seg * 65536;
    unsigned short* dst = (seg == 1) ? zb : wb;

    const int tid  = threadIdx.x;
    const int bm0  = tloc * 128;
    const int wid  = tid >> 6;
    const int lane = tid & 63;
    const int lm   = lane & 15;
    const int lh   = lane >> 4;
    const int wm   = wid >> 2;
    const int wn   = wid & 3;
    const int wbase = tid & ~63;

    f32x4 cacc[4][4];
#pragma unroll
    for (int i = 0; i < 4; i++)
#pragma unroll
        for (int j = 0; j < 4; j++) cacc[i][j] = (f32x4){0.f, 0.f, 0.f, 0.f};

    for (int k0 = 0; k0 < 256; k0 += 32) {
        {
            int row = tid >> 2;
            int g   = (tid & 3) ^ ((row >> 1) & 3);
            int gr  = bm0 + row;
            if (gr > nrows - 1) gr = nrows - 1;
            async16(Asrc + (size_t)gr * 256 + k0 + g * 8,
                    As + (size_t)wbase * 8);
        }
#pragma unroll
        for (int ss = 0; ss < 2; ss++) {
            int i   = ss * 512 + tid;
            int row = i >> 2;
            int g   = (i & 3) ^ ((row >> 1) & 3);
            async16(wsel + (size_t)row * 256 + k0 + g * 8,
                    Bs + (size_t)(ss * 512 + wbase) * 8);
        }
        asm volatile("s_waitcnt vmcnt(0)" ::: "memory");
        __syncthreads();

        bf16x8 a[4], bfr[4];
#pragma unroll
        for (int i = 0; i < 4; i++) {
            int rr = wm * 64 + i * 16 + lm;
            a[i] = *(const bf16x8*)(As + rr * 32 + ((lh ^ ((rr >> 1) & 3)) * 8));
        }
#pragma unroll
        for (int j = 0; j < 4; j++) {
            int rr = wn * 64 + j * 16 + lm;
            bfr[j] = *(const bf16x8*)(Bs + rr * 32 + ((lh ^ ((rr >> 1) & 3)) * 8));
        }
#pragma unroll
        for (int i = 0; i < 4; i++)
#pragma unroll
            for (int j = 0; j < 4; j++)
                cacc[i][j] = __builtin_amdgcn_mfma_f32_16x16x32_bf16(
                    bfr[j], a[i], cacc[i][j], 0, 0, 0);
        __syncthreads();
    }

#pragma unroll
    for (int i = 0; i < 4; i++) {
        int grow = bm0 + wm * 64 + i * 16 + lm;
        if (grow < nrows) {
#pragma unroll
            for (int j = 0; j < 4; j++) {
                int col = wn * 64 + j * 16 + lh * 4;
                ushort4 r;
                r.x = f2bf(cacc[i][j][0]);
                r.y = f2bf(cacc[i][j][1]);
                r.z = f2bf(cacc[i][j][2]);
                r.w = f2bf(cacc[i][j][3]);
                *(ushort4*)(dst + (size_t)grow * 256 + col) = r;
            }
        }
    }
}

// BM=64, 256 threads (4 waves, wave wn owns cols wn*64..+63 of all 64 rows)
__global__ __launch_bounds__(256) void gemm_y1_relu(
    unsigned short* __restrict__ xb,          // A source AND x_next dst
    const unsigned short* __restrict__ wt,    // seg0 weights (W1)
    const unsigned short* __restrict__ wb,    // tri rows (q@W2)
    const unsigned short* __restrict__ zb,    // node rows (s@W0)
    const int* __restrict__ en,
    const int* __restrict__ eoff,
    const int* __restrict__ eadj,
    const float* __restrict__ wl,
    float* __restrict__ p,
    int last)
{
    // 32 KB: K-loop uses [0,20KB) as As|Bs; epilogue reuses the whole
    // buffer as the 64x256 bf16 C-tile.
    __shared__ __align__(16) unsigned short smem[64 * 256];
    unsigned short* const As = smem;              // 64*32  = 4 KB
    unsigned short* const Bs = smem + 64 * 32;    // 256*32 = 16 KB

    const int b    = blockIdx.x;
    const int tile = (b & 7) * TPX64 + (b >> 3);  // 2344 = 8*293, bijective

    const int tid  = threadIdx.x;
    const int bm0  = tile * 64;
    const int wid  = tid >> 6;                    // 0..3
    const int lane = tid & 63;
    const int lm   = lane & 15;
    const int lh   = lane >> 4;
    const int wn   = wid;
    const int wbase = tid & ~63;

    f32x4 cacc[4][4];
#pragma unroll
    for (int i = 0; i < 4; i++)
#pragma unroll
        for (int j = 0; j < 4; j++) cacc[i][j] = (f32x4){0.f, 0.f, 0.f, 0.f};

    for (int k0 = 0; k0 < 256; k0 += 32) {
        // A: 64 rows x 32k = 256 granules, one per thread
        {
            int row = tid >> 2;                       // 0..63
            int g   = (tid & 3) ^ ((row >> 1) & 3);
            int gr  = bm0 + row;
            if (gr > M_EDGES - 1) gr = M_EDGES - 1;
            async16(xb + (size_t)gr * 256 + k0 + g * 8,
                    As + (size_t)wbase * 8);
        }
        // B: 256 rows x 32k = 1024 granules, four per thread
#pragma unroll
        for (int ss = 0; ss < 4; ss++) {
            int i   = ss * 256 + tid;
            int row = i >> 2;
            int g   = (i & 3) ^ ((row >> 1) & 3);
            async16(wt + (size_t)row * 256 + k0 + g * 8,
                    Bs + (size_t)(ss * 256 + wbase) * 8);
        }
        asm volatile("s_waitcnt vmcnt(0)" ::: "memory");
        __syncthreads();

        bf16x8 a[4], bfr[4];
#pragma unroll
        for (int i = 0; i < 4; i++) {
            int rr = i * 16 + lm;                     // rows 0..63
            a[i] = *(const bf16x8*)(As + rr * 32 + ((lh ^ ((rr >> 1) & 3)) * 8));
        }
#pragma unroll
        for (int j = 0; j < 4; j++) {
            int rr = wn * 64 + j * 16 + lm;
            bfr[j] = *(const bf16x8*)(Bs + rr * 32 + ((lh ^ ((rr >> 1) & 3)) * 8));
        }
#pragma unroll
        for (int i = 0; i < 4; i++)
#pragma unroll
            for (int j = 0; j < 4; j++)
                cacc[i][j] = __builtin_amdgcn_mfma_f32_16x16x32_bf16(
                    bfr[j], a[i], cacc[i][j], 0, 0, 0);
        __syncthreads();
    }

    // --- retire ALL of cacc to LDS (frees the 64 acc VGPRs before gather),
    // bf16, XOR-swizzled by row ---
#pragma unroll
    for (int i = 0; i < 4; i++) {
        int lr  = i * 16 + lm;                        // 0..63
        int key = (lr & 7) << 4;
#pragma unroll
        for (int j = 0; j < 4; j++) {
            int colb = wn * 128 + j * 32 + lh * 8;    // byte offset in row
            ushort4 r;
            r.x = f2bf(cacc[i][j][0]);
            r.y = f2bf(cacc[i][j][1]);
            r.z = f2bf(cacc[i][j][2]);
            r.w = f2bf(cacc[i][j][3]);
            *(ushort4*)((char*)smem + (size_t)lr * 512 + (colb ^ key)) = r;
        }
    }
    __syncthreads();

    // --- fused relu: 2 edges per wave per iteration (independent gather
    // chains overlap); fully-coalesced 512B/wave row loads ---
    const int f = lane * 4;
    for (int k = 0; k < 8; k++) {
        int lr0 = k * 8 + wid;                        // 0..59
        int lr1 = lr0 + 4;
        int e0  = bm0 + lr0;
        if (e0 >= M_EDGES) break;                     // wave-uniform
        int e1  = bm0 + lr1;
        int ok1 = (e1 < M_EDGES);
        int e1c = ok1 ? e1 : (M_EDGES - 1);

        ushort4 yv0 = *(const ushort4*)((const char*)smem + (size_t)lr0 * 512 +
                                        ((lane * 8) ^ ((lr0 & 7) << 4)));
        ushort4 yv1 = *(const ushort4*)((const char*)smem + (size_t)lr1 * 512 +
                                        ((lane * 8) ^ ((lr1 & 7) << 4)));
        int u0 = en[2 * e0], v0 = en[2 * e0 + 1];
        int u1 = en[2 * e1c], v1 = en[2 * e1c + 1];
        ushort4 zv0 = *(const ushort4*)(zb + (size_t)v0 * 256 + f);
        ushort4 zu0 = *(const ushort4*)(zb + (size_t)u0 * 256 + f);
        ushort4 zv1 = *(const ushort4*)(zb + (size_t)v1 * 256 + f);
        ushort4 zu1 = *(const ushort4*)(zb + (size_t)u1 * 256 + f);
        int beg0 = eoff[e0], end0 = eoff[e0 + 1];
        int beg1 = eoff[e1c], end1 = eoff[e1c + 1];

        float s0x = bf2f(yv0.x) + bf2f(zv0.x) - bf2f(zu0.x);
        float s0y = bf2f(yv0.y) + bf2f(zv0.y) - bf2f(zu0.y);
        float s0z = bf2f(yv0.z) + bf2f(zv0.z) - bf2f(zu0.z);
        float s0w = bf2f(yv0.w) + bf2f(zv0.w) - bf2f(zu0.w);
        float s1x = bf2f(yv1.x) + bf2f(zv1.x) - bf2f(zu1.x);
        float s1y = bf2f(yv1.y) + bf2f(zv1.y) - bf2f(zu1.y);
        float s1z = bf2f(yv1.z) + bf2f(zv1.z) - bf2f(zu1.z);
        float s1w = bf2f(yv1.w) + bf2f(zv1.w) - bf2f(zu1.w);

        for (int i2 = beg0; i2 < end0; i2++) {
            int ta = eadj[i2];
            float sa = (ta & 1) ? -1.f : 1.f;
            ushort4 wa = *(const ushort4*)(wb + (size_t)(ta >> 1) * 256 + f);
            s0x += sa * bf2f(wa.x);
            s0y += sa * bf2f(wa.y);
            s0z += sa * bf2f(wa.z);
            s0w += sa * bf2f(wa.w);
        }
        for (int i2 = beg1; i2 < end1; i2++) {
            int ta = eadj[i2];
            float sa = (ta & 1) ? -1.f : 1.f;
            ushort4 wa = *(const ushort4*)(wb + (size_t)(ta >> 1) * 256 + f);
            s1x += sa * bf2f(wa.x);
            s1y += sa * bf2f(wa.y);
            s1z += sa * bf2f(wa.z);
            s1w += sa * bf2f(wa.w);
        }

        s0x = fmaxf(s0x, 0.f); s0y = fmaxf(s0y, 0.f);
        s0z = fmaxf(s0z, 0.f); s0w = fmaxf(s0w, 0.f);
        s1x = fmaxf(s1x, 0.f); s1y = fmaxf(s1y, 0.f);
        s1z = fmaxf(s1z, 0.f); s1w = fmaxf(s1w, 0.f);

        if (!last) {
            ushort4 r0;
            r0.x = f2bf(s0x); r0.y = f2bf(s0y);
            r0.z = f2bf(s0z); r0.w = f2bf(s0w);
            *(ushort4*)(xb + (size_t)e0 * 256 + f) = r0;
            if (ok1) {
                ushort4 r1;
                r1.x = f2bf(s1x); r1.y = f2bf(s1y);
                r1.z = f2bf(s1z); r1.w = f2bf(s1w);
                *(ushort4*)(xb + (size_t)e1 * 256 + f) = r1;
            }
        } else {
            float4 wv = *(const float4*)(wl + f);
            float d0 = s0x * wv.x + s0y * wv.y + s0z * wv.z + s0w * wv.w;
            float d1 = s1x * wv.x + s1y * wv.y + s1z * wv.z + s1w * wv.w;
#pragma unroll
            for (int off = 32; off > 0; off >>= 1) {
                d0 += __shfl_down(d0, off, 64);
                d1 += __shfl_down(d1, off, 64);
            }
            if (lane == 0) {
                p[e0] = d0;
                if (ok1) p[e1] = d1;
            }
        }
    }
}

// ---------------------------------------------------------------------------
// CSR build
// ---------------------------------------------------------------------------
__global__ __launch_bounds__(256) void count_nodes(
    const int* __restrict__ en, int* __restrict__ cnt)
{
    int e = blockIdx.x * 256 + threadIdx.x;
    if (e < M_EDGES) {
        atomicAdd(&cnt[en[2 * e]], 1);
        atomicAdd(&cnt[en[2 * e + 1]], 1);
    }
}

__global__ __launch_bounds__(256) void count_tris(
    const int* __restrict__ te, int* __restrict__ cnt)
{
    int t = blockIdx.x * 256 + threadIdx.x;
    if (t < N_TRIS) {
#pragma unroll
        for (int k = 0; k < 3; k++) atomicAdd(&cnt[te[3 * t + k]], 1);
    }
}

__global__ __launch_bounds__(256) void scan_block(
    const int* __restrict__ cnt, int* __restrict__ off,
    int* __restrict__ partial, int n)
{
    __shared__ int s[256];
    int t = threadIdx.x;
    int gid = blockIdx.x * 256 + t;
    int v = (gid < n) ? cnt[gid] : 0;
    s[t] = v;
    __syncthreads();
    for (int o = 1; o < 256; o <<= 1) {
        int x = (t >= o) ? s[t - o] : 0;
        __syncthreads();
        s[t] += x;
        __syncthreads();
    }
    if (gid < n) off[gid] = s[t] - v;
    if (t == 255) partial[blockIdx.x] = s[255];
}

__global__ __launch_bounds__(1024) void scan_partial(int* __restrict__ partial, int nb)
{
    __shared__ int s[1024];
    int t = threadIdx.x;
    int v = (t < nb) ? partial[t] : 0;
    s[t] = v;
    __syncthreads();
    for (int o = 1; o < 1024; o <<= 1) {
        int x = (t >= o) ? s[t - o] : 0;
        __syncthreads();
        s[t] += x;
        __syncthreads();
    }
    if (t < nb) partial[t] = s[t] - v;
}

__global__ __launch_bounds__(256) void scan_add(
    int* __restrict__ off, int* __restrict__ cursor,
    const int* __restrict__ partial, int n, int total)
{
    int gid = blockIdx.x * 256 + threadIdx.x;
    if (gid == 0) off[n] = total;
    if (gid < n) {
        int o = off[gid] + partial[blockIdx.x];
        off[gid] = o;
        cursor[gid] = o;
    }
}

__global__ __launch_bounds__(256) void fill_nodes(
    const int* __restrict__ en, int* __restrict__ cursor, int* __restrict__ adj)
{
    int e = blockIdx.x * 256 + threadIdx.x;
    if (e < M_EDGES) {
        int u = en[2 * e], v = en[2 * e + 1];
        adj[atomicAdd(&cursor[u], 1)] = (e << 1);        // u endpoint: minus
        adj[atomicAdd(&cursor[v], 1)] = (e << 1) | 1;    // v endpoint: plus
    }
}

__global__ __launch_bounds__(256) void fill_tris(
    const int* __restrict__ te, const int* __restrict__ ts,
    int* __restrict__ cursor, int* __restrict__ adj)
{
    int t = blockIdx.x * 256 + threadIdx.x;
    if (t < N_TRIS) {
#pragma unroll
        for (int k = 0; k < 3; k++) {
            int e = te[3 * t + k];
            int neg = (ts[3 * t + k] < 0) ? 1 : 0;
            adj[atomicAdd(&cursor[e], 1)] = (t << 1) | neg;
        }
    }
}

// ---------------------------------------------------------------------------
// Aggregation pass (pre-GEMM):
//   blocks [0, ZN_BLOCKS)        : s[n] = sum (+/-) x[e]   (node CSR)
//   blocks [ZN_BLOCKS, +WT)      : q[t] = sum s_k * x[e_k] (tri direct)
// ---------------------------------------------------------------------------
#define ZN_BLOCKS (NN_NODES / 4)
#define WT_BLOCKS (N_TRIS / 4)

__global__ __launch_bounds__(256) void agg_fused(
    const unsigned short* __restrict__ xb,
    const int* __restrict__ noff,
    const int* __restrict__ nadj,
    unsigned short* __restrict__ sbuf,
    const int* __restrict__ te,
    const int* __restrict__ ts,
    unsigned short* __restrict__ qbuf)
{
    int lane = threadIdx.x & 63;
    int f = lane * 4;
    if (blockIdx.x < ZN_BLOCKS) {
        int n = blockIdx.x * 4 + (threadIdx.x >> 6);
        int beg = noff[n], end = noff[n + 1];
        int deg = end - beg;
        // one-shot adjacency prefetch: lane l holds entry l (valid l<deg)
        int cl = beg + lane;
        if (cl > 2 * M_EDGES - 1) cl = 2 * M_EDGES - 1;
        int entL = nadj[cl];
        int dmax = (deg < 64) ? deg : 64;
        float ax = 0.f, ay = 0.f, az = 0.f, aw = 0.f;
        int j = 0;
        for (; j + 1 < dmax; j += 2) {
            int ea = __shfl(entL, j, 64);
            int eb = __shfl(entL, j + 1, 64);
            float sa = (ea & 1) ? 1.f : -1.f;
            float sgb = (eb & 1) ? 1.f : -1.f;
            ushort4 va = *(const ushort4*)(xb + (size_t)(ea >> 1) * 256 + f);
            ushort4 vb = *(const ushort4*)(xb + (size_t)(eb >> 1) * 256 + f);
            ax += sa * bf2f(va.x) + sgb * bf2f(vb.x);
            ay += sa * bf2f(va.y) + sgb * bf2f(vb.y);
            az += sa * bf2f(va.z) + sgb * bf2f(vb.z);
            aw += sa * bf2f(va.w) + sgb * bf2f(vb.w);
        }
        if (j < dmax) {
            int ea = __shfl(entL, j, 64);
            float sa = (ea & 1) ? 1.f : -1.f;
            ushort4 va = *(const ushort4*)(xb + (size_t)(ea >> 1) * 256 + f);
            ax += sa * bf2f(va.x);
            ay += sa * bf2f(va.y);
            az += sa * bf2f(va.z);
            aw += sa * bf2f(va.w);
        }
        for (int i = beg + 64; i < end; i++) {   // rare deg>64 fallback
            int ea = nadj[i];
            float sa = (ea & 1) ? 1.f : -1.f;
            ushort4 va = *(const ushort4*)(xb + (size_t)(ea >> 1) * 256 + f);
            ax += sa * bf2f(va.x);
            ay += sa * bf2f(va.y);
            az += sa * bf2f(va.z);
            aw += sa * bf2f(va.w);
        }
        ushort4 r;
        r.x = f2bf(ax); r.y = f2bf(ay); r.z = f2bf(az); r.w = f2bf(aw);
        *(ushort4*)(sbuf + (size_t)n * 256 + f) = r;
    } else {
        int t = (blockIdx.x - ZN_BLOCKS) * 4 + (threadIdx.x >> 6);
        int e0 = te[3 * t + 0], e1 = te[3 * t + 1], e2 = te[3 * t + 2];
        float s0 = (float)ts[3 * t + 0];
        float s1 = (float)ts[3 * t + 1];
        float s2 = (float)ts[3 * t + 2];
        ushort4 a4 = *(const ushort4*)(xb + (size_t)e0 * 256 + f);
        ushort4 b4 = *(const ushort4*)(xb + (size_t)e1 * 256 + f);
        ushort4 d4 = *(const ushort4*)(xb + (size_t)e2 * 256 + f);
        ushort4 r;
        r.x = f2bf(s0 * bf2f(a4.x) + s1 * bf2f(b4.x) + s2 * bf2f(d4.x));
        r.y = f2bf(s0 * bf2f(a4.y) + s1 * bf2f(b4.y) + s2 * bf2f(d4.y));
        r.z = f2bf(s0 * bf2f(a4.z) + s1 * bf2f(b4.z) + s2 * bf2f(d4.z));
        r.w = f2bf(s0 * bf2f(a4.w) + s1 * bf2f(b4.w) + s2 * bf2f(d4.w));
        *(ushort4*)(qbuf + (size_t)t * 256 + f) = r;
    }
}

__global__ __launch_bounds__(256) void out_nodes(
    const float* __restrict__ p,
    const int* __restrict__ noff,
    const int* __restrict__ nadj,
    float* __restrict__ out)
{
    int n = blockIdx.x * 256 + threadIdx.x;
    if (n >= NN_NODES) return;
    int beg = noff[n], end = noff[n + 1];
    float s = 0.f;
    for (int i = beg; i < end; i++) {
        int ent = nadj[i];
        float sg = (ent & 1) ? 1.f : -1.f;
        s += sg * p[ent >> 1];
    }
    out[n] = s;
}

// ---------------------------------------------------------------------------
// Conversions
// ---------------------------------------------------------------------------
__global__ __launch_bounds__(256) void cvt_x(
    const float* __restrict__ x, unsigned short* __restrict__ xb)
{
    int idx = blockIdx.x * 256 + threadIdx.x;
    float4 v = *(const float4*)(x + (size_t)idx * 4);
    ushort4 r;
    r.x = f2bf(v.x); r.y = f2bf(v.y); r.z = f2bf(v.z); r.w = f2bf(v.w);
    *(ushort4*)(xb + (size_t)idx * 4) = r;
}

// wt[l][seg][n][k], seg order = (W1, W0, W2) matching GEMM segments
__global__ __launch_bounds__(256) void cvt_w(
    const float* __restrict__ W0, const float* __restrict__ W1,
    const float* __restrict__ W2, unsigned short* __restrict__ wt)
{
    int idx = blockIdx.x * 256 + threadIdx.x;   // 4*3*65536 total
    int l = idx / (3 * 65536);
    int rem = idx - l * (3 * 65536);
    int seg = rem >> 16;
    int n = (rem >> 8) & 255;
    int k = rem & 255;
    const float* src = (seg == 0) ? W1 : (seg == 1) ? W0 : W2;
    wt[idx] = f2bf(src[(size_t)l * 65536 + k * 256 + n]);
}

extern "C" void kernel_launch(void* const* d_in, const int* in_sizes, int n_in,
                              void* d_out, int out_size, void* d_ws, size_t ws_size,
                              hipStream_t stream)
{
    const float* x0  = (const float*)d_in[0];
    const float* W0s = (const float*)d_in[1];
    const float* W1s = (const float*)d_in[2];
    const float* W2s = (const float*)d_in[3];
    const float* WL  = (const float*)d_in[4];
    const int*   en  = (const int*)d_in[5];
    const int*   te  = (const int*)d_in[6];
    const int*   ts  = (const int*)d_in[7];
    float* out = (float*)d_out;

    const size_t MF = (size_t)M_EDGES * F;
    unsigned short* xb = (unsigned short*)d_ws;          // MF
    unsigned short* y1 = xb + MF;                        // MF (unused now)
    unsigned short* sbuf = y1 + MF;                      // NN*256
    unsigned short* qbuf = sbuf + (size_t)NN_NODES * 256;// N_TRIS*256
    unsigned short* wt = qbuf + (size_t)N_TRIS * 256;    // 4*3*65536
    unsigned short* wb = wt + (size_t)4 * 3 * 65536;     // N_TRIS*256
    unsigned short* zb = wb + (size_t)N_TRIS * 256;      // NN*256
    float* p = (float*)(zb + (size_t)NN_NODES * 256);    // M f32
    int* noff = (int*)(p + M_EDGES);                     // NN+1
    int* ncur = noff + (NN_NODES + 1);                   // NN
    int* nadj = ncur + NN_NODES;                         // 2*M
    int* eoff = nadj + 2 * M_EDGES;                      // M+1
    int* ecur = eoff + (M_EDGES + 1);                    // M
    int* eadj = ecur + M_EDGES;                          // 3*N_TRIS
    int* part = eadj + 3 * N_TRIS;                       // 1024

    cvt_w<<<(4 * 3 * 65536) / 256, 256, 0, stream>>>(W0s, W1s, W2s, wt);
    cvt_x<<<(int)(MF / 4 / 256), 256, 0, stream>>>(x0, xb);

    const int nbN = (NN_NODES + 255) / 256;
    const int nbE = (M_EDGES + 255) / 256;
    hipMemsetAsync(ncur, 0, NN_NODES * sizeof(int), stream);
    hipMemsetAsync(ecur, 0, M_EDGES * sizeof(int), stream);
    count_nodes<<<nbE, 256, 0, stream>>>(en, ncur);
    count_tris<<<(N_TRIS + 255) / 256, 256, 0, stream>>>(te, ecur);
    scan_block<<<nbN, 256, 0, stream>>>(ncur, noff, part, NN_NODES);
    scan_partial<<<1, 1024, 0, stream>>>(part, nbN);
    scan_add<<<nbN, 256, 0, stream>>>(noff, ncur, part, NN_NODES, 2 * M_EDGES);
    fill_nodes<<<nbE, 256, 0, stream>>>(en, ncur, nadj);
    scan_block<<<nbE, 256, 0, stream>>>(ecur, eoff, part, M_EDGES);
    scan_partial<<<1, 1024, 0, stream>>>(part, nbE);
    scan_add<<<nbE, 256, 0, stream>>>(eoff, ecur, part, M_EDGES, 3 * N_TRIS);
    fill_tris<<<(N_TRIS + 255) / 256, 256, 0, stream>>>(te, ts, ecur, eadj);

    for (int l = 0; l < NLAYERS; l++) {
        agg_fused<<<ZN_BLOCKS + WT_BLOCKS, 256, 0, stream>>>(
            xb, noff, nadj, sbuf, te, ts, qbuf);
        gemm_zw<<<ZW_PAD, 512, 0, stream>>>(
            sbuf, qbuf, wt + (size_t)l * 3 * 65536, zb, wb);
        gemm_y1_relu<<<T0_64, 256, 0, stream>>>(
            xb, wt + (size_t)l * 3 * 65536, wb, zb, en, eoff, eadj,
            WL, p, (l == NLAYERS - 1) ? 1 : 0);
    }

    out_nodes<<<(NN_NODES + 255) / 256, 256, 0, stream>>>(p, noff, nadj, out);
}